// Round 5
// baseline (2290.604 us; speedup 1.0000x reference)
//
#include <hip/hip_runtime.h>
#include <math.h>

#define NNODES 20000
#define NEDGES 320000
#define NGRAPHS 200
#define K1 36
#define K2 26
#define NBINS 20480   // 1024 threads x 20 bins in the scan kernel (>= NNODES)

struct WPtrs { const float* w[6]; };

__device__ __forceinline__ float sigf(float v) { return 1.0f / (1.0f + expf(-v)); }
__device__ __forceinline__ float eluf(float v) { return v > 0.0f ? v : expm1f(v); }

// fast (v_exp_f32 / v_rcp_f32) variants for the edge hot loop
__device__ __forceinline__ float fsig(float v) { return __builtin_amdgcn_rcpf(1.0f + __expf(-v)); }
__device__ __forceinline__ float felu(float v) { return v > 0.0f ? v : __expf(v) - 1.0f; }

// ---------------------------------------------------------------------------
// Generic fused GEMM: out[:, chunk*128+half*64 : +64] = act(A[M,128] @ Wc[128,64])
// grid.x = ceil(M/64), grid.y = nchunks*2. 64x64 output tile per workgroup.
// ---------------------------------------------------------------------------
__global__ __launch_bounds__(256) void gemm128_kernel(
    const float* __restrict__ A, WPtrs wp, float* __restrict__ out,
    int out_stride, int act)
{
    __shared__ float4 Wl[2048];   // [k][f4]: k*16 + fq   (128 x 64 floats)
    __shared__ float4 Al[2048];   // [n][k4]: n*32 + k4   (64 x 128 floats)

    const int half  = blockIdx.y & 1;
    const int chunk = blockIdx.y >> 1;
    const float4* W4 = (const float4*)(wp.w[chunk] + half * 64);

    for (int idx = threadIdx.x; idx < 2048; idx += 256) {
        int k = idx >> 4, fq = idx & 15;
        Wl[idx] = W4[k * 32 + fq];           // row stride of W is 128 floats = 32 f4
    }
    const int m0 = blockIdx.x * 64;
    const float4* A4 = (const float4*)A;
    for (int idx = threadIdx.x; idx < 2048; idx += 256) {
        int r = idx >> 5, k4 = idx & 31;
        int row = m0 + r;
        Al[idx] = (row < NNODES) ? A4[(size_t)row * 32 + k4] : make_float4(0.f, 0.f, 0.f, 0.f);
    }
    __syncthreads();

    const int fg = threadIdx.x & 15;   // feature group: f' = fg*4
    const int ng = threadIdx.x >> 4;   // node group: n = ng*4 + j

    float acc[4][4] = {};
    #pragma unroll 4
    for (int k4 = 0; k4 < 32; ++k4) {
        float4 a[4], w[4];
        #pragma unroll
        for (int j = 0; j < 4; ++j) a[j] = Al[(ng * 4 + j) * 32 + k4];
        #pragma unroll
        for (int q = 0; q < 4; ++q) w[q] = Wl[(k4 * 4 + q) * 16 + fg];
        #pragma unroll
        for (int j = 0; j < 4; ++j) {
            const float* ap = (const float*)&a[j];
            #pragma unroll
            for (int q = 0; q < 4; ++q) {
                const float* wq = (const float*)&w[q];
                #pragma unroll
                for (int jj = 0; jj < 4; ++jj)
                    acc[j][jj] = fmaf(ap[q], wq[jj], acc[j][jj]);
            }
        }
    }

    const int coff = chunk * 128 + half * 64 + fg * 4;
    #pragma unroll
    for (int j = 0; j < 4; ++j) {
        int row = m0 + ng * 4 + j;
        if (row < NNODES) {
            float4 v; float* vp = (float*)&v;
            #pragma unroll
            for (int jj = 0; jj < 4; ++jj) {
                float t = acc[j][jj];
                vp[jj] = act ? sigf(t) : t;
            }
            *(float4*)(out + (size_t)row * out_stride + coff) = v;
        }
    }
}

// ---------------------------------------------------------------------------
// Edge-permutation build: counting sort of edge indices by source node.
// Sources are invariant across the 3 GNN blocks -> build once, use 3x.
// ---------------------------------------------------------------------------
__global__ void hist_kernel(const int* __restrict__ esrc, int* __restrict__ cnt)
{
    int i = blockIdx.x * 256 + threadIdx.x;
    if (i < NEDGES) atomicAdd(&cnt[esrc[i]], 1);
}

__global__ __launch_bounds__(1024) void scan_kernel(
    const int* __restrict__ cnt, int* __restrict__ cursor)
{
    __shared__ int ps[1024];
    const int t = threadIdx.x;
    const int b0 = t * 20;
    int sum = 0;
    #pragma unroll
    for (int b = 0; b < 20; ++b) sum += cnt[b0 + b];
    ps[t] = sum;
    __syncthreads();
    // inclusive scan over 1024 partials
    for (int off = 1; off < 1024; off <<= 1) {
        int v = (t >= off) ? ps[t - off] : 0;
        __syncthreads();
        ps[t] += v;
        __syncthreads();
    }
    int acc = ps[t] - sum;          // exclusive prefix of this thread's chunk
    #pragma unroll
    for (int b = 0; b < 20; ++b) {
        int c = cnt[b0 + b];
        cursor[b0 + b] = acc;
        acc += c;
    }
}

__global__ void scatter_kernel(const int* __restrict__ esrc,
                               int* __restrict__ cursor, int* __restrict__ eperm)
{
    int i = blockIdx.x * 256 + threadIdx.x;
    if (i < NEDGES) {
        int p = atomicAdd(&cursor[esrc[i]], 1);
        eperm[p] = i;
    }
}

// materialize sorted edge metadata (kills the eperm->esrc->P 3-deep chain)
__global__ void reorder_meta_kernel(const int* __restrict__ eperm,
                                    const int* __restrict__ esrc,
                                    const int* __restrict__ etgt,
                                    const float* __restrict__ dist,
                                    int* __restrict__ esrc_s,
                                    int* __restrict__ etgt_s,
                                    float* __restrict__ dist_s)
{
    int j = blockIdx.x * 256 + threadIdx.x;
    if (j < NEDGES) {
        int e = eperm[j];
        esrc_s[j] = esrc[e];
        etgt_s[j] = etgt[e];
        dist_s[j] = dist[e];
    }
}

// ---------------------------------------------------------------------------
// Edge kernel: z = sigmoid(g)*elu(m)*(cs@W1v + (pw@W2v)*sigmoid(pw@W2vg))
// g/m reconstructed from gathered node-level products P[n][6][128].
//
// R2 post-mortem: sort cut FETCH 679->491MB / WRITE 160->47MB but the
//   eperm->esrc->P readfirstlane chain made it latency-bound (dur 411).
// R4 post-mortem: prefetch+materialized metadata fixed the latency (BW
//   2.6 TB/s flowing) but FETCH jumped to 783MB and WRITE to 860MB with
//   VGPR_Count pinned at 64: the +16 live prefetch registers pushed the
//   peak live set (~77) past the 64-reg allocation -> per-iteration scratch
//   spills (~530-820MB store+reload) = the entire regression.
// R5: __launch_bounds__(512, 2) raises the register budget (min 2 waves/EU
//   -> up to ~256 VGPRs). LDS (45KB) still allows 3 blocks/CU. Everything
//   else identical to R4.
// 512 threads = 4 slots x 128 features; slot = 16 contiguous edges,
// 4-edge groups x 4 iterations; 64 edges per block.
// ---------------------------------------------------------------------------
__global__ __launch_bounds__(512, 2) void edge_kernel(
    const float* __restrict__ P, const int* __restrict__ eperm,
    const int* __restrict__ esrc_s, const int* __restrict__ etgt_s,
    const float* __restrict__ dist_s,
    const float* __restrict__ cs, const float* __restrict__ pw,
    const float* __restrict__ W1v, const float* __restrict__ W2v,
    const float* __restrict__ W2vg,
    float* __restrict__ x)
{
    __shared__ float wl[(K1 + 2 * K2) * 128];   // 88 x 128 floats = 45 KB

    for (int idx = threadIdx.x; idx < K1 * 128; idx += 512) wl[idx] = W1v[idx];
    for (int idx = threadIdx.x; idx < K2 * 128; idx += 512) wl[K1 * 128 + idx] = W2v[idx];
    for (int idx = threadIdx.x; idx < K2 * 128; idx += 512) wl[(K1 + K2) * 128 + idx] = W2vg[idx];

    const int f    = threadIdx.x & 127;
    const int esub = threadIdx.x >> 7;            // wave-uniform slot id
    const int base = blockIdx.x * 64 + esub * 16; // 16 contiguous edges per slot

    // prologue: group 0 metadata as plain vector values (1-hop contiguous)
    int ev[4], sv[4], tv[4]; float dv[4];
    #pragma unroll
    for (int u = 0; u < 4; ++u) {
        ev[u] = eperm[base + u];
        sv[u] = esrc_s[base + u];
        tv[u] = etgt_s[base + u];
        dv[u] = dist_s[base + u];
    }

    __syncthreads();

    int   run_s   = -1;
    float run_acc = 0.f;

    #pragma unroll 1
    for (int it = 0; it < 4; ++it) {
        // convert to wave-uniform scalars at the use site (vmcnt wait lands here)
        int e[4], s[4], t[4]; float dd[4];
        #pragma unroll
        for (int u = 0; u < 4; ++u) {
            e[u]  = __builtin_amdgcn_readfirstlane(ev[u]);
            s[u]  = __builtin_amdgcn_readfirstlane(sv[u]);
            t[u]  = __builtin_amdgcn_readfirstlane(tv[u]);
            dd[u] = dv[u];
        }

        // issue all 32 P-gathers up front (scalar base + lane offset);
        // sorted order makes the s[u]-side rows cache-resident
        float g0[4], g1[4], g2t[4], g2s[4], m0[4], m1[4], m2t[4], m2s[4];
        #pragma unroll
        for (int u = 0; u < 4; ++u) {
            const float* Ps = P + (size_t)s[u] * 768;
            const float* Pt = P + (size_t)t[u] * 768;
            g0[u]  = Ps[f];
            g2s[u] = Ps[256 + f];
            m0[u]  = Ps[384 + f];
            m2s[u] = Ps[640 + f];
            g1[u]  = Pt[128 + f];
            g2t[u] = Pt[256 + f];
            m1[u]  = Pt[512 + f];
            m2t[u] = Pt[640 + f];
        }

        // prefetch next group's metadata (no readfirstlane -> no wait here)
        if (it < 3) {
            #pragma unroll
            for (int u = 0; u < 4; ++u) {
                int j = base + (it + 1) * 4 + u;
                ev[u] = eperm[j];
                sv[u] = esrc_s[j];
                tv[u] = etgt_s[j];
                dv[u] = dist_s[j];
            }
        }

        // edge-feature dot products, k outermost: each LDS weight read is
        // amortized over 4 edges; cs/pw rows are wave-uniform -> scalar loads
        // whose latency overlaps the P-gather waits
        float z1[4] = {}, za[4] = {}, zb[4] = {};
        #pragma unroll
        for (int k = 0; k < K1; ++k) {
            const float wv = wl[k * 128 + f];
            #pragma unroll
            for (int u = 0; u < 4; ++u)
                z1[u] = fmaf(cs[(size_t)e[u] * K1 + k], wv, z1[u]);
        }
        #pragma unroll
        for (int k = 0; k < K2; ++k) {
            const float wa = wl[(K1 + k) * 128 + f];
            const float wb = wl[(K1 + K2 + k) * 128 + f];
            #pragma unroll
            for (int u = 0; u < 4; ++u) {
                const float p = pw[(size_t)e[u] * K2 + k];
                za[u] = fmaf(p, wa, za[u]);
                zb[u] = fmaf(p, wb, zb[u]);
            }
        }

        float z[4];
        #pragma unroll
        for (int u = 0; u < 4; ++u) {
            const float invd = __builtin_amdgcn_rcpf(dd[u]);
            const float g = g0[u] + g1[u] + (g2t[u] - g2s[u]) * invd;
            const float m = m0[u] + m1[u] + (m2t[u] - m2s[u]) * invd;
            z[u] = fsig(g) * felu(m) * (z1[u] + za[u] * fsig(zb[u]));
        }

        // merge same-source runs across the whole 16-edge slot
        #pragma unroll
        for (int u = 0; u < 4; ++u) {
            if (s[u] == run_s) {
                run_acc += z[u];
            } else {
                if (run_s >= 0) atomicAdd(x + (size_t)run_s * 128 + f, run_acc);
                run_s   = s[u];
                run_acc = z[u];
            }
        }
    }
    atomicAdd(x + (size_t)run_s * 128 + f, run_acc);
}

// ---------------------------------------------------------------------------
// Pool + psi elementwise: T[n][3][128] = [x@Wp1, x@Wp2, x@Wpsi]
// pools[g] += elu(T0)*T1 ; xout = elu(T2)
// ---------------------------------------------------------------------------
__global__ __launch_bounds__(256) void pool_psi_kernel(
    const float* __restrict__ T, const int* __restrict__ gidx,
    float* __restrict__ pools, float* __restrict__ xout)
{
    int idx = blockIdx.x * 256 + threadIdx.x;
    int n = idx >> 7, f = idx & 127;
    float h1 = eluf(T[(size_t)n * 384 + f]);
    float h2 = T[(size_t)n * 384 + 128 + f];
    atomicAdd(pools + (size_t)gidx[n] * 128 + f, h1 * h2);
    xout[(size_t)n * 128 + f] = eluf(T[(size_t)n * 384 + 256 + f]);
}

// ---------------------------------------------------------------------------
// Final head: per graph: elu(@Wlr1[128,64]) -> elu(@Wlr2[64,42]) -> @Wlr3[42,1]
// ---------------------------------------------------------------------------
__global__ __launch_bounds__(64) void final_kernel(
    const float* __restrict__ pools,
    const float* __restrict__ Wlr1, const float* __restrict__ Wlr2,
    const float* __restrict__ Wlr3, float* __restrict__ out)
{
    __shared__ float h1[64];
    __shared__ float h2[42];
    const int g = blockIdx.x;
    const int f = threadIdx.x;

    float a = 0.f;
    #pragma unroll 8
    for (int k = 0; k < 128; ++k) a = fmaf(pools[(size_t)g * 128 + k], Wlr1[k * 64 + f], a);
    h1[f] = eluf(a);
    __syncthreads();
    if (f < 42) {
        float b = 0.f;
        #pragma unroll
        for (int k = 0; k < 64; ++k) b = fmaf(h1[k], Wlr2[k * 42 + f], b);
        h2[f] = eluf(b);
    }
    __syncthreads();
    if (f == 0) {
        float c = 0.f;
        #pragma unroll
        for (int k = 0; k < 42; ++k) c = fmaf(h2[k], Wlr3[k], c);
        out[g] = c;
    }
}

__global__ void zero_kernel(float* p, int n)
{
    int i = blockIdx.x * 256 + threadIdx.x;
    if (i < n) p[i] = 0.f;
}

extern "C" void kernel_launch(void* const* d_in, const int* in_sizes, int n_in,
                              void* d_out, int out_size, void* d_ws, size_t ws_size,
                              hipStream_t stream)
{
    const float* nodes = (const float*)d_in[0];
    const int*   esrc  = (const int*)d_in[1];
    const int*   etgt  = (const int*)d_in[2];
    const float* dist  = (const float*)d_in[3];
    const int*   gidx  = (const int*)d_in[4];
    // d_in[5] = node_counts : unused (division discarded in the source)
    const float* cs    = (const float*)d_in[6];
    const float* pw    = (const float*)d_in[7];
    const float* W_emb = (const float*)d_in[8];
    const float* Wg    = (const float*)d_in[9];
    const float* Wm    = (const float*)d_in[10];
    const float* W1v   = (const float*)d_in[11];
    const float* W2v   = (const float*)d_in[12];
    const float* W2vg  = (const float*)d_in[13];
    const float* Wp1   = (const float*)d_in[14];
    const float* Wp2   = (const float*)d_in[15];
    const float* Wpsi  = (const float*)d_in[16];
    const float* Wlr1  = (const float*)d_in[17];
    const float* Wlr2  = (const float*)d_in[18];
    const float* Wlr3  = (const float*)d_in[19];
    float* outp = (float*)d_out;

    // workspace layout (floats):
    // xA | xB | P(=T overlay) | pools | cnt | cursor | eperm | esrc_s | etgt_s | dist_s
    float* xA    = (float*)d_ws;
    float* xB    = xA + (size_t)NNODES * 128;
    float* P     = xB + (size_t)NNODES * 128;
    float* pools = P + (size_t)NNODES * 768;     // ~82 MB so far
    int* cnt     = (int*)(pools + NGRAPHS * 128);
    int* cursor  = cnt + NBINS;
    int* eperm   = cursor + NBINS;
    int* esrc_s  = eperm + NEDGES;
    int* etgt_s  = esrc_s + NEDGES;
    float* dist_s = (float*)(etgt_s + NEDGES);   // +5.3 MB total

    zero_kernel<<<100, 256, 0, stream>>>(pools, NGRAPHS * 128);

    // build source-sorted edge permutation (sources invariant across blocks)
    zero_kernel<<<(NBINS + 255) / 256, 256, 0, stream>>>((float*)cnt, NBINS);
    hist_kernel<<<(NEDGES + 255) / 256, 256, 0, stream>>>(esrc, cnt);
    scan_kernel<<<1, 1024, 0, stream>>>(cnt, cursor);
    scatter_kernel<<<(NEDGES + 255) / 256, 256, 0, stream>>>(esrc, cursor, eperm);
    reorder_meta_kernel<<<(NEDGES + 255) / 256, 256, 0, stream>>>(
        eperm, esrc, etgt, dist, esrc_s, etgt_s, dist_s);

    // x = sigmoid(nodes @ W_emb)
    {
        WPtrs wp{}; wp.w[0] = W_emb;
        gemm128_kernel<<<dim3(313, 2), 256, 0, stream>>>(nodes, wp, xA, 128, 1);
    }

    float* xc = xA;
    float* xn = xB;
    for (int i = 0; i < 3; ++i) {
        // P = x @ [Wg0,Wg1,Wg2,Wm0,Wm1,Wm2]  (each 128x128, contiguous in Wg/Wm)
        WPtrs wp{};
        const float* Wgi = Wg + (size_t)i * 49152;
        const float* Wmi = Wm + (size_t)i * 49152;
        wp.w[0] = Wgi;          wp.w[1] = Wgi + 16384;  wp.w[2] = Wgi + 32768;
        wp.w[3] = Wmi;          wp.w[4] = Wmi + 16384;  wp.w[5] = Wmi + 32768;
        gemm128_kernel<<<dim3(313, 12), 256, 0, stream>>>(xc, wp, P, 768, 0);

        // gather/combine/scatter over edges in source-sorted order
        edge_kernel<<<5000, 512, 0, stream>>>(P, eperm, esrc_s, etgt_s, dist_s,
            cs, pw,
            W1v + (size_t)i * (K1 * 128),
            W2v + (size_t)i * (K2 * 128),
            W2vg + (size_t)i * (K2 * 128), xc);

        // T = x @ [Wp1, Wp2, Wpsi]  (reuse P buffer)
        WPtrs wq{};
        wq.w[0] = Wp1 + (size_t)i * 16384;
        wq.w[1] = Wp2 + (size_t)i * 16384;
        wq.w[2] = Wpsi + (size_t)i * 16384;
        gemm128_kernel<<<dim3(313, 6), 256, 0, stream>>>(xc, wq, P, 384, 0);

        // pools[g] += elu(T0)*T1 ; xn = elu(T2)
        pool_psi_kernel<<<10000, 256, 0, stream>>>(P, gidx, pools, xn);

        float* tmp = xc; xc = xn; xn = tmp;
    }

    final_kernel<<<NGRAPHS, 64, 0, stream>>>(pools, Wlr1, Wlr2, Wlr3, outp);
}

// Round 6
// 1428.567 us; speedup vs baseline: 1.6034x; 1.6034x over previous
//
#include <hip/hip_runtime.h>
#include <math.h>

#define NNODES 20000
#define NEDGES 320000
#define NGRAPHS 200
#define K1 36
#define K2 26
#define NBINS 20480   // 1024 threads x 20 bins in the scan kernel (>= NNODES)

struct WPtrs { const float* w[6]; };

__device__ __forceinline__ float sigf(float v) { return 1.0f / (1.0f + expf(-v)); }
__device__ __forceinline__ float eluf(float v) { return v > 0.0f ? v : expm1f(v); }

// fast (v_exp_f32 / v_rcp_f32) variants for the edge hot loop
__device__ __forceinline__ float fsig(float v) { return __builtin_amdgcn_rcpf(1.0f + __expf(-v)); }
__device__ __forceinline__ float felu(float v) { return v > 0.0f ? v : __expf(v) - 1.0f; }

// ---------------------------------------------------------------------------
// Generic fused GEMM: out[:, chunk*128+half*64 : +64] = act(A[M,128] @ Wc[128,64])
// grid.x = ceil(M/64), grid.y = nchunks*2. 64x64 output tile per workgroup.
// ---------------------------------------------------------------------------
__global__ __launch_bounds__(256) void gemm128_kernel(
    const float* __restrict__ A, WPtrs wp, float* __restrict__ out,
    int out_stride, int act)
{
    __shared__ float4 Wl[2048];   // [k][f4]: k*16 + fq   (128 x 64 floats)
    __shared__ float4 Al[2048];   // [n][k4]: n*32 + k4   (64 x 128 floats)

    const int half  = blockIdx.y & 1;
    const int chunk = blockIdx.y >> 1;
    const float4* W4 = (const float4*)(wp.w[chunk] + half * 64);

    for (int idx = threadIdx.x; idx < 2048; idx += 256) {
        int k = idx >> 4, fq = idx & 15;
        Wl[idx] = W4[k * 32 + fq];           // row stride of W is 128 floats = 32 f4
    }
    const int m0 = blockIdx.x * 64;
    const float4* A4 = (const float4*)A;
    for (int idx = threadIdx.x; idx < 2048; idx += 256) {
        int r = idx >> 5, k4 = idx & 31;
        int row = m0 + r;
        Al[idx] = (row < NNODES) ? A4[(size_t)row * 32 + k4] : make_float4(0.f, 0.f, 0.f, 0.f);
    }
    __syncthreads();

    const int fg = threadIdx.x & 15;   // feature group: f' = fg*4
    const int ng = threadIdx.x >> 4;   // node group: n = ng*4 + j

    float acc[4][4] = {};
    #pragma unroll 4
    for (int k4 = 0; k4 < 32; ++k4) {
        float4 a[4], w[4];
        #pragma unroll
        for (int j = 0; j < 4; ++j) a[j] = Al[(ng * 4 + j) * 32 + k4];
        #pragma unroll
        for (int q = 0; q < 4; ++q) w[q] = Wl[(k4 * 4 + q) * 16 + fg];
        #pragma unroll
        for (int j = 0; j < 4; ++j) {
            const float* ap = (const float*)&a[j];
            #pragma unroll
            for (int q = 0; q < 4; ++q) {
                const float* wq = (const float*)&w[q];
                #pragma unroll
                for (int jj = 0; jj < 4; ++jj)
                    acc[j][jj] = fmaf(ap[q], wq[jj], acc[j][jj]);
            }
        }
    }

    const int coff = chunk * 128 + half * 64 + fg * 4;
    #pragma unroll
    for (int j = 0; j < 4; ++j) {
        int row = m0 + ng * 4 + j;
        if (row < NNODES) {
            float4 v; float* vp = (float*)&v;
            #pragma unroll
            for (int jj = 0; jj < 4; ++jj) {
                float t = acc[j][jj];
                vp[jj] = act ? sigf(t) : t;
            }
            *(float4*)(out + (size_t)row * out_stride + coff) = v;
        }
    }
}

// ---------------------------------------------------------------------------
// Edge-permutation build: counting sort of edge indices by source node.
// Sources are invariant across the 3 GNN blocks -> build once, use 3x.
// ---------------------------------------------------------------------------
__global__ void hist_kernel(const int* __restrict__ esrc, int* __restrict__ cnt)
{
    int i = blockIdx.x * 256 + threadIdx.x;
    if (i < NEDGES) atomicAdd(&cnt[esrc[i]], 1);
}

__global__ __launch_bounds__(1024) void scan_kernel(
    const int* __restrict__ cnt, int* __restrict__ cursor)
{
    __shared__ int ps[1024];
    const int t = threadIdx.x;
    const int b0 = t * 20;
    int sum = 0;
    #pragma unroll
    for (int b = 0; b < 20; ++b) sum += cnt[b0 + b];
    ps[t] = sum;
    __syncthreads();
    // inclusive scan over 1024 partials
    for (int off = 1; off < 1024; off <<= 1) {
        int v = (t >= off) ? ps[t - off] : 0;
        __syncthreads();
        ps[t] += v;
        __syncthreads();
    }
    int acc = ps[t] - sum;          // exclusive prefix of this thread's chunk
    #pragma unroll
    for (int b = 0; b < 20; ++b) {
        int c = cnt[b0 + b];
        cursor[b0 + b] = acc;
        acc += c;
    }
}

__global__ void scatter_kernel(const int* __restrict__ esrc,
                               int* __restrict__ cursor, int* __restrict__ eperm)
{
    int i = blockIdx.x * 256 + threadIdx.x;
    if (i < NEDGES) {
        int p = atomicAdd(&cursor[esrc[i]], 1);
        eperm[p] = i;
    }
}

// materialize sorted edge metadata (arithmetic index -> pure s_load chains)
__global__ void reorder_meta_kernel(const int* __restrict__ eperm,
                                    const int* __restrict__ esrc,
                                    const int* __restrict__ etgt,
                                    const float* __restrict__ dist,
                                    int* __restrict__ esrc_s,
                                    int* __restrict__ etgt_s,
                                    float* __restrict__ dist_s)
{
    int j = blockIdx.x * 256 + threadIdx.x;
    if (j < NEDGES) {
        int e = eperm[j];
        esrc_s[j] = esrc[e];
        etgt_s[j] = etgt[e];
        dist_s[j] = dist[e];
    }
}

// ---------------------------------------------------------------------------
// Edge kernel: z = sigmoid(g)*elu(m)*(cs@W1v + (pw@W2v)*sigmoid(pw@W2vg))
// g/m reconstructed from gathered node-level products P[n][6][128].
//
// R5 post-mortem: spills fixed (WRITE 860->19MB, FETCH->436MB) but dur
//   STUCK at 640us with HBM 9% / VALU 38% / occ 23% -- same 640 as R4
//   despite 3.6x less traffic => the floor is the VECTOR-load metadata
//   prefetch consumed via readfirstlane: metadata sits on the vmcnt path
//   entangled with gathers+atomics, forcing per-iteration waits on atomic
//   acknowledge latency. R1 (280us, 3TB/s, VALU 75%) prefetched metadata
//   via SGPR-indexed loads => s_load on the scalar/lgkmcnt path, fully
//   decoupled from vector memory.
// R6: R1 skeleton + sorted edges with ARITHMETIC indexing (sorted arrays
//   esrc_s/etgt_s/dist_s/eperm indexed by position j = s_load chain
//   identical to R1) + 2-edge k-outer unroll (halves per-edge weight-read
//   fat) + per-thread cross-iteration run-merge of same-source atomics
//   (sorted runs ~8 within a thread's stream).
// 256 threads = 2 slots x 128 features; thread handles edges {j, j+1},
// j = blk*64 + it*4 + esub*2; 16 iterations; 64 edges per block.
// ---------------------------------------------------------------------------
__global__ __launch_bounds__(256, 2) void edge_kernel(
    const float* __restrict__ P, const int* __restrict__ eperm,
    const int* __restrict__ esrc_s, const int* __restrict__ etgt_s,
    const float* __restrict__ dist_s,
    const float* __restrict__ cs, const float* __restrict__ pw,
    const float* __restrict__ W1v, const float* __restrict__ W2v,
    const float* __restrict__ W2vg,
    float* __restrict__ x)
{
    const int f    = threadIdx.x & 127;

    // weight columns for this feature, pinned resident (land in AGPRs, R1)
    float w1[K1], w2[K2], w2g[K2];
    #pragma unroll
    for (int k = 0; k < K1; ++k) w1[k]  = W1v[k * 128 + f];
    #pragma unroll
    for (int k = 0; k < K2; ++k) w2[k]  = W2v[k * 128 + f];
    #pragma unroll
    for (int k = 0; k < K2; ++k) w2g[k] = W2vg[k * 128 + f];
    #pragma unroll
    for (int k = 0; k < K1; ++k) asm volatile("" : "+v"(w1[k]));
    #pragma unroll
    for (int k = 0; k < K2; ++k) asm volatile("" : "+v"(w2[k]));
    #pragma unroll
    for (int k = 0; k < K2; ++k) asm volatile("" : "+v"(w2g[k]));

    const int esub = __builtin_amdgcn_readfirstlane(threadIdx.x >> 7); // 0/1
    const int base = __builtin_amdgcn_readfirstlane(blockIdx.x * 64 + esub * 2);

    // prologue: iteration-0 metadata; j is SGPR -> these are s_loads
    int   e0 = eperm[base],      e1 = eperm[base + 1];
    int   s0 = esrc_s[base],     s1 = esrc_s[base + 1];
    int   t0 = etgt_s[base],     t1 = etgt_s[base + 1];
    float d0 = dist_s[base],     d1 = dist_s[base + 1];

    int   run_s   = -1;
    float run_acc = 0.f;

    #pragma unroll 1
    for (int it = 0; it < 16; ++it) {
        // snapshot current scalars (prefetch below overwrites)
        const int   ce0 = e0, ce1 = e1, cs0 = s0, cs1 = s1, ct0 = t0, ct1 = t1;
        const float cd0 = d0, cd1 = d1;

        // issue the 16 P-gathers first (long-latency; scalar base + lane f)
        const float* Ps0 = P + (size_t)cs0 * 768;
        const float* Pt0 = P + (size_t)ct0 * 768;
        const float* Ps1 = P + (size_t)cs1 * 768;
        const float* Pt1 = P + (size_t)ct1 * 768;
        float g0a = Ps0[f],       g0b = Ps1[f];
        float g2sa = Ps0[256 + f], g2sb = Ps1[256 + f];
        float m0a = Ps0[384 + f], m0b = Ps1[384 + f];
        float m2sa = Ps0[640 + f], m2sb = Ps1[640 + f];
        float g1a = Pt0[128 + f], g1b = Pt1[128 + f];
        float g2ta = Pt0[256 + f], g2tb = Pt1[256 + f];
        float m1a = Pt0[512 + f], m1b = Pt1[512 + f];
        float m2ta = Pt0[640 + f], m2tb = Pt1[640 + f];

        // scalar prefetch of next iteration's metadata (s_load / lgkmcnt path,
        // decoupled from the vmcnt gather+atomic queue -- the R1 mechanism)
        if (it < 15) {
            const int jn = base + (it + 1) * 4;
            e0 = eperm[jn];   e1 = eperm[jn + 1];
            s0 = esrc_s[jn];  s1 = esrc_s[jn + 1];
            t0 = etgt_s[jn];  t1 = etgt_s[jn + 1];
            d0 = dist_s[jn];  d1 = dist_s[jn + 1];
        }

        // edge-feature dot products, k outermost: each pinned weight read
        // amortized over 2 edges; cs/pw rows are wave-uniform (SGPR base)
        const float* c0 = cs + (size_t)ce0 * K1;
        const float* c1 = cs + (size_t)ce1 * K1;
        const float* p0 = pw + (size_t)ce0 * K2;
        const float* p1 = pw + (size_t)ce1 * K2;
        float z1a = 0.f, z1b = 0.f;
        #pragma unroll
        for (int k = 0; k < K1; ++k) {
            const float wv = w1[k];
            z1a = fmaf(c0[k], wv, z1a);
            z1b = fmaf(c1[k], wv, z1b);
        }
        float zaa = 0.f, zba = 0.f, zab = 0.f, zbb = 0.f;
        #pragma unroll
        for (int k = 0; k < K2; ++k) {
            const float wa = w2[k], wb = w2g[k];
            const float pa = p0[k], pb = p1[k];
            zaa = fmaf(pa, wa, zaa);
            zba = fmaf(pa, wb, zba);
            zab = fmaf(pb, wa, zab);
            zbb = fmaf(pb, wb, zbb);
        }

        const float i0 = __builtin_amdgcn_rcpf(cd0);
        const float i1 = __builtin_amdgcn_rcpf(cd1);
        const float ga = g0a + g1a + (g2ta - g2sa) * i0;
        const float ma = m0a + m1a + (m2ta - m2sa) * i0;
        const float gb = g0b + g1b + (g2tb - g2sb) * i1;
        const float mb = m0b + m1b + (m2tb - m2sb) * i1;
        const float za = fsig(ga) * felu(ma) * (z1a + zaa * fsig(zba));
        const float zb = fsig(gb) * felu(mb) * (z1b + zab * fsig(zbb));

        // merge same-source runs across iterations (sorted -> long runs);
        // branches are on SGPR values -> wave-uniform, no divergence
        if (cs0 == run_s) {
            run_acc += za;
        } else {
            if (run_s >= 0) atomicAdd(x + (size_t)run_s * 128 + f, run_acc);
            run_s = cs0; run_acc = za;
        }
        if (cs1 == run_s) {
            run_acc += zb;
        } else {
            atomicAdd(x + (size_t)run_s * 128 + f, run_acc);
            run_s = cs1; run_acc = zb;
        }
    }
    atomicAdd(x + (size_t)run_s * 128 + f, run_acc);
}

// ---------------------------------------------------------------------------
// Pool + psi elementwise: T[n][3][128] = [x@Wp1, x@Wp2, x@Wpsi]
// pools[g] += elu(T0)*T1 ; xout = elu(T2)
// ---------------------------------------------------------------------------
__global__ __launch_bounds__(256) void pool_psi_kernel(
    const float* __restrict__ T, const int* __restrict__ gidx,
    float* __restrict__ pools, float* __restrict__ xout)
{
    int idx = blockIdx.x * 256 + threadIdx.x;
    int n = idx >> 7, f = idx & 127;
    float h1 = eluf(T[(size_t)n * 384 + f]);
    float h2 = T[(size_t)n * 384 + 128 + f];
    atomicAdd(pools + (size_t)gidx[n] * 128 + f, h1 * h2);
    xout[(size_t)n * 128 + f] = eluf(T[(size_t)n * 384 + 256 + f]);
}

// ---------------------------------------------------------------------------
// Final head: per graph: elu(@Wlr1[128,64]) -> elu(@Wlr2[64,42]) -> @Wlr3[42,1]
// ---------------------------------------------------------------------------
__global__ __launch_bounds__(64) void final_kernel(
    const float* __restrict__ pools,
    const float* __restrict__ Wlr1, const float* __restrict__ Wlr2,
    const float* __restrict__ Wlr3, float* __restrict__ out)
{
    __shared__ float h1[64];
    __shared__ float h2[42];
    const int g = blockIdx.x;
    const int f = threadIdx.x;

    float a = 0.f;
    #pragma unroll 8
    for (int k = 0; k < 128; ++k) a = fmaf(pools[(size_t)g * 128 + k], Wlr1[k * 64 + f], a);
    h1[f] = eluf(a);
    __syncthreads();
    if (f < 42) {
        float b = 0.f;
        #pragma unroll
        for (int k = 0; k < 64; ++k) b = fmaf(h1[k], Wlr2[k * 42 + f], b);
        h2[f] = eluf(b);
    }
    __syncthreads();
    if (f == 0) {
        float c = 0.f;
        #pragma unroll
        for (int k = 0; k < 42; ++k) c = fmaf(h2[k], Wlr3[k], c);
        out[g] = c;
    }
}

__global__ void zero_kernel(float* p, int n)
{
    int i = blockIdx.x * 256 + threadIdx.x;
    if (i < n) p[i] = 0.f;
}

extern "C" void kernel_launch(void* const* d_in, const int* in_sizes, int n_in,
                              void* d_out, int out_size, void* d_ws, size_t ws_size,
                              hipStream_t stream)
{
    const float* nodes = (const float*)d_in[0];
    const int*   esrc  = (const int*)d_in[1];
    const int*   etgt  = (const int*)d_in[2];
    const float* dist  = (const float*)d_in[3];
    const int*   gidx  = (const int*)d_in[4];
    // d_in[5] = node_counts : unused (division discarded in the source)
    const float* cs    = (const float*)d_in[6];
    const float* pw    = (const float*)d_in[7];
    const float* W_emb = (const float*)d_in[8];
    const float* Wg    = (const float*)d_in[9];
    const float* Wm    = (const float*)d_in[10];
    const float* W1v   = (const float*)d_in[11];
    const float* W2v   = (const float*)d_in[12];
    const float* W2vg  = (const float*)d_in[13];
    const float* Wp1   = (const float*)d_in[14];
    const float* Wp2   = (const float*)d_in[15];
    const float* Wpsi  = (const float*)d_in[16];
    const float* Wlr1  = (const float*)d_in[17];
    const float* Wlr2  = (const float*)d_in[18];
    const float* Wlr3  = (const float*)d_in[19];
    float* outp = (float*)d_out;

    // workspace layout (floats):
    // xA | xB | P(=T overlay) | pools | cnt | cursor | eperm | esrc_s | etgt_s | dist_s
    float* xA    = (float*)d_ws;
    float* xB    = xA + (size_t)NNODES * 128;
    float* P     = xB + (size_t)NNODES * 128;
    float* pools = P + (size_t)NNODES * 768;     // ~82 MB so far
    int* cnt     = (int*)(pools + NGRAPHS * 128);
    int* cursor  = cnt + NBINS;
    int* eperm   = cursor + NBINS;
    int* esrc_s  = eperm + NEDGES;
    int* etgt_s  = esrc_s + NEDGES;
    float* dist_s = (float*)(etgt_s + NEDGES);   // +5.3 MB total

    zero_kernel<<<100, 256, 0, stream>>>(pools, NGRAPHS * 128);

    // build source-sorted edge permutation (sources invariant across blocks)
    zero_kernel<<<(NBINS + 255) / 256, 256, 0, stream>>>((float*)cnt, NBINS);
    hist_kernel<<<(NEDGES + 255) / 256, 256, 0, stream>>>(esrc, cnt);
    scan_kernel<<<1, 1024, 0, stream>>>(cnt, cursor);
    scatter_kernel<<<(NEDGES + 255) / 256, 256, 0, stream>>>(esrc, cursor, eperm);
    reorder_meta_kernel<<<(NEDGES + 255) / 256, 256, 0, stream>>>(
        eperm, esrc, etgt, dist, esrc_s, etgt_s, dist_s);

    // x = sigmoid(nodes @ W_emb)
    {
        WPtrs wp{}; wp.w[0] = W_emb;
        gemm128_kernel<<<dim3(313, 2), 256, 0, stream>>>(nodes, wp, xA, 128, 1);
    }

    float* xc = xA;
    float* xn = xB;
    for (int i = 0; i < 3; ++i) {
        // P = x @ [Wg0,Wg1,Wg2,Wm0,Wm1,Wm2]  (each 128x128, contiguous in Wg/Wm)
        WPtrs wp{};
        const float* Wgi = Wg + (size_t)i * 49152;
        const float* Wmi = Wm + (size_t)i * 49152;
        wp.w[0] = Wgi;          wp.w[1] = Wgi + 16384;  wp.w[2] = Wgi + 32768;
        wp.w[3] = Wmi;          wp.w[4] = Wmi + 16384;  wp.w[5] = Wmi + 32768;
        gemm128_kernel<<<dim3(313, 12), 256, 0, stream>>>(xc, wp, P, 768, 0);

        // gather/combine/scatter over edges in source-sorted order
        edge_kernel<<<5000, 256, 0, stream>>>(P, eperm, esrc_s, etgt_s, dist_s,
            cs, pw,
            W1v + (size_t)i * (K1 * 128),
            W2v + (size_t)i * (K2 * 128),
            W2vg + (size_t)i * (K2 * 128), xc);

        // T = x @ [Wp1, Wp2, Wpsi]  (reuse P buffer)
        WPtrs wq{};
        wq.w[0] = Wp1 + (size_t)i * 16384;
        wq.w[1] = Wp2 + (size_t)i * 16384;
        wq.w[2] = Wpsi + (size_t)i * 16384;
        gemm128_kernel<<<dim3(313, 6), 256, 0, stream>>>(xc, wq, P, 384, 0);

        // pools[g] += elu(T0)*T1 ; xn = elu(T2)
        pool_psi_kernel<<<10000, 256, 0, stream>>>(P, gidx, pools, xn);

        float* tmp = xc; xc = xn; xn = tmp;
    }

    final_kernel<<<NGRAPHS, 64, 0, stream>>>(pools, Wlr1, Wlr2, Wlr3, outp);
}

// Round 7
// 1312.459 us; speedup vs baseline: 1.7453x; 1.0885x over previous
//
#include <hip/hip_runtime.h>
#include <math.h>

#define NNODES 20000
#define NEDGES 320000
#define NGRAPHS 200
#define K1 36
#define K2 26
#define NBINS 20480   // 1024 threads x 20 bins in the scan kernel (>= NNODES)

struct WPtrs { const float* w[6]; };

__device__ __forceinline__ float sigf(float v) { return 1.0f / (1.0f + expf(-v)); }
__device__ __forceinline__ float eluf(float v) { return v > 0.0f ? v : expm1f(v); }

// fast (v_exp_f32 / v_rcp_f32) variants for the edge hot loop
__device__ __forceinline__ float fsig(float v) { return __builtin_amdgcn_rcpf(1.0f + __expf(-v)); }
__device__ __forceinline__ float felu(float v) { return v > 0.0f ? v : __expf(v) - 1.0f; }

// ---------------------------------------------------------------------------
// Generic fused GEMM: out[:, chunk*128+half*64 : +64] = act(A[M,128] @ Wc[128,64])
// grid.x = ceil(M/64), grid.y = nchunks*2. 64x64 output tile per workgroup.
// ---------------------------------------------------------------------------
__global__ __launch_bounds__(256) void gemm128_kernel(
    const float* __restrict__ A, WPtrs wp, float* __restrict__ out,
    int out_stride, int act)
{
    __shared__ float4 Wl[2048];   // [k][f4]: k*16 + fq   (128 x 64 floats)
    __shared__ float4 Al[2048];   // [n][k4]: n*32 + k4   (64 x 128 floats)

    const int half  = blockIdx.y & 1;
    const int chunk = blockIdx.y >> 1;
    const float4* W4 = (const float4*)(wp.w[chunk] + half * 64);

    for (int idx = threadIdx.x; idx < 2048; idx += 256) {
        int k = idx >> 4, fq = idx & 15;
        Wl[idx] = W4[k * 32 + fq];           // row stride of W is 128 floats = 32 f4
    }
    const int m0 = blockIdx.x * 64;
    const float4* A4 = (const float4*)A;
    for (int idx = threadIdx.x; idx < 2048; idx += 256) {
        int r = idx >> 5, k4 = idx & 31;
        int row = m0 + r;
        Al[idx] = (row < NNODES) ? A4[(size_t)row * 32 + k4] : make_float4(0.f, 0.f, 0.f, 0.f);
    }
    __syncthreads();

    const int fg = threadIdx.x & 15;   // feature group: f' = fg*4
    const int ng = threadIdx.x >> 4;   // node group: n = ng*4 + j

    float acc[4][4] = {};
    #pragma unroll 4
    for (int k4 = 0; k4 < 32; ++k4) {
        float4 a[4], w[4];
        #pragma unroll
        for (int j = 0; j < 4; ++j) a[j] = Al[(ng * 4 + j) * 32 + k4];
        #pragma unroll
        for (int q = 0; q < 4; ++q) w[q] = Wl[(k4 * 4 + q) * 16 + fg];
        #pragma unroll
        for (int j = 0; j < 4; ++j) {
            const float* ap = (const float*)&a[j];
            #pragma unroll
            for (int q = 0; q < 4; ++q) {
                const float* wq = (const float*)&w[q];
                #pragma unroll
                for (int jj = 0; jj < 4; ++jj)
                    acc[j][jj] = fmaf(ap[q], wq[jj], acc[j][jj]);
            }
        }
    }

    const int coff = chunk * 128 + half * 64 + fg * 4;
    #pragma unroll
    for (int j = 0; j < 4; ++j) {
        int row = m0 + ng * 4 + j;
        if (row < NNODES) {
            float4 v; float* vp = (float*)&v;
            #pragma unroll
            for (int jj = 0; jj < 4; ++jj) {
                float t = acc[j][jj];
                vp[jj] = act ? sigf(t) : t;
            }
            *(float4*)(out + (size_t)row * out_stride + coff) = v;
        }
    }
}

// ---------------------------------------------------------------------------
// Edge-permutation build: counting sort of edge indices by source node.
// Sources are invariant across the 3 GNN blocks -> build once, use 3x.
// ---------------------------------------------------------------------------
__global__ void hist_kernel(const int* __restrict__ esrc, int* __restrict__ cnt)
{
    int i = blockIdx.x * 256 + threadIdx.x;
    if (i < NEDGES) atomicAdd(&cnt[esrc[i]], 1);
}

__global__ __launch_bounds__(1024) void scan_kernel(
    const int* __restrict__ cnt, int* __restrict__ cursor)
{
    __shared__ int ps[1024];
    const int t = threadIdx.x;
    const int b0 = t * 20;
    int sum = 0;
    #pragma unroll
    for (int b = 0; b < 20; ++b) sum += cnt[b0 + b];
    ps[t] = sum;
    __syncthreads();
    // inclusive scan over 1024 partials
    for (int off = 1; off < 1024; off <<= 1) {
        int v = (t >= off) ? ps[t - off] : 0;
        __syncthreads();
        ps[t] += v;
        __syncthreads();
    }
    int acc = ps[t] - sum;          // exclusive prefix of this thread's chunk
    #pragma unroll
    for (int b = 0; b < 20; ++b) {
        int c = cnt[b0 + b];
        cursor[b0 + b] = acc;
        acc += c;
    }
}

__global__ void scatter_kernel(const int* __restrict__ esrc,
                               int* __restrict__ cursor, int* __restrict__ eperm)
{
    int i = blockIdx.x * 256 + threadIdx.x;
    if (i < NEDGES) {
        int p = atomicAdd(&cursor[esrc[i]], 1);
        eperm[p] = i;
    }
}

// materialize sorted edge metadata (arithmetic index -> pure s_load chains)
__global__ void reorder_meta_kernel(const int* __restrict__ eperm,
                                    const int* __restrict__ esrc,
                                    const int* __restrict__ etgt,
                                    const float* __restrict__ dist,
                                    int* __restrict__ esrc_s,
                                    int* __restrict__ etgt_s,
                                    float* __restrict__ dist_s)
{
    int j = blockIdx.x * 256 + threadIdx.x;
    if (j < NEDGES) {
        int e = eperm[j];
        esrc_s[j] = esrc[e];
        etgt_s[j] = etgt[e];
        dist_s[j] = dist[e];
    }
}

// ---------------------------------------------------------------------------
// Edge kernel: z = sigmoid(g)*elu(m)*(cs@W1v + (pw@W2v)*sigmoid(pw@W2vg))
// g/m reconstructed from gathered node-level products P[n][6][128].
//
// R6 post-mortem: 319us, VALU 58% = 185us issue = ~711 instr per 2-edge
//   iteration vs ~250 necessary. The gap: 124 per-lane cs/pw element loads
//   (compiler can't prove invariance vs the x atomics -> per-lane
//   global_load + 64-bit addressing ~3 slots each, lane-redundant).
// R7: stage the block's 64 sorted-edge cs/pw rows in LDS ONCE (16KB, one
//   barrier, coalesced row gather of the same 79MB these loads already
//   fetched), then k-loop reads ds_read_b128 at wave-uniform addresses
//   (broadcast, conflict-free): 124 global loads/iter -> 32 ds_b128.
//   eperm leaves the hot loop (staging only). Everything else = R6.
// 256 threads = 2 slots x 128 features; thread handles edges {j, j+1},
// j = blk*64 + it*4 + esub*2; 16 iterations; 64 edges per block.
// ---------------------------------------------------------------------------
__global__ __launch_bounds__(256, 2) void edge_kernel(
    const float* __restrict__ P, const int* __restrict__ eperm,
    const int* __restrict__ esrc_s, const int* __restrict__ etgt_s,
    const float* __restrict__ dist_s,
    const float* __restrict__ cs, const float* __restrict__ pw,
    const float* __restrict__ W1v, const float* __restrict__ W2v,
    const float* __restrict__ W2vg,
    float* __restrict__ x)
{
    __shared__ float rows[64][64];  // [local edge][0:36 cs | 36:62 pw | 62:64 zero]

    const int f = threadIdx.x & 127;

    // weight columns for this feature, pinned resident
    float w1[K1], w2[K2], w2g[K2];
    #pragma unroll
    for (int k = 0; k < K1; ++k) w1[k]  = W1v[k * 128 + f];
    #pragma unroll
    for (int k = 0; k < K2; ++k) w2[k]  = W2v[k * 128 + f];
    #pragma unroll
    for (int k = 0; k < K2; ++k) w2g[k] = W2vg[k * 128 + f];
    #pragma unroll
    for (int k = 0; k < K1; ++k) asm volatile("" : "+v"(w1[k]));
    #pragma unroll
    for (int k = 0; k < K2; ++k) asm volatile("" : "+v"(w2[k]));
    #pragma unroll
    for (int k = 0; k < K2; ++k) asm volatile("" : "+v"(w2g[k]));

    // stage this block's 64 edge rows: rows[le] = [cs(36) | pw(26) | 0,0]
    {
        const int le = threadIdx.x >> 2;        // 0..63
        const int c0 = threadIdx.x & 3;
        const int e  = eperm[blockIdx.x * 64 + le];
        const float* crow = cs + (size_t)e * K1;
        const float* prow = pw + (size_t)e * K2;
        #pragma unroll
        for (int c = c0; c < 64; c += 4) {
            float v = 0.f;
            if (c < K1) v = crow[c];
            else if (c < K1 + K2) v = prow[c - K1];
            rows[le][c] = v;
        }
    }

    const int esub = __builtin_amdgcn_readfirstlane(threadIdx.x >> 7); // 0/1
    const int base = __builtin_amdgcn_readfirstlane(blockIdx.x * 64 + esub * 2);

    // prologue: iteration-0 metadata; index is SGPR-uniform -> scalar path
    int   s0 = esrc_s[base],     s1 = esrc_s[base + 1];
    int   t0 = etgt_s[base],     t1 = etgt_s[base + 1];
    float d0 = dist_s[base],     d1 = dist_s[base + 1];

    __syncthreads();

    int   run_s   = -1;
    float run_acc = 0.f;

    #pragma unroll 1
    for (int it = 0; it < 16; ++it) {
        // snapshot current scalars (prefetch below overwrites)
        const int   cs0 = s0, cs1 = s1, ct0 = t0, ct1 = t1;
        const float cd0 = d0, cd1 = d1;

        // issue the 16 P-gathers first (long-latency; scalar base + lane f)
        const float* Ps0 = P + (size_t)cs0 * 768;
        const float* Pt0 = P + (size_t)ct0 * 768;
        const float* Ps1 = P + (size_t)cs1 * 768;
        const float* Pt1 = P + (size_t)ct1 * 768;
        float g0a = Ps0[f],        g0b = Ps1[f];
        float g2sa = Ps0[256 + f], g2sb = Ps1[256 + f];
        float m0a = Ps0[384 + f],  m0b = Ps1[384 + f];
        float m2sa = Ps0[640 + f], m2sb = Ps1[640 + f];
        float g1a = Pt0[128 + f],  g1b = Pt1[128 + f];
        float g2ta = Pt0[256 + f], g2tb = Pt1[256 + f];
        float m1a = Pt0[512 + f],  m1b = Pt1[512 + f];
        float m2ta = Pt0[640 + f], m2tb = Pt1[640 + f];

        // scalar prefetch of next iteration's metadata (decoupled path)
        if (it < 15) {
            const int jn = base + (it + 1) * 4;
            s0 = esrc_s[jn];  s1 = esrc_s[jn + 1];
            t0 = etgt_s[jn];  t1 = etgt_s[jn + 1];
            d0 = dist_s[jn];  d1 = dist_s[jn + 1];
        }

        // edge-feature dot products from LDS rows (wave-uniform broadcast
        // ds_read_b128: 32 per iteration instead of 124 global loads)
        const int l0 = it * 4 + esub * 2;
        const int l1 = l0 + 1;
        float z1a = 0.f, z1b = 0.f;
        #pragma unroll
        for (int k4 = 0; k4 < 9; ++k4) {
            const float4 ca = *(const float4*)&rows[l0][k4 * 4];
            const float4 cb = *(const float4*)&rows[l1][k4 * 4];
            const float* cav = (const float*)&ca;
            const float* cbv = (const float*)&cb;
            #pragma unroll
            for (int jj = 0; jj < 4; ++jj) {
                z1a = fmaf(cav[jj], w1[k4 * 4 + jj], z1a);
                z1b = fmaf(cbv[jj], w1[k4 * 4 + jj], z1b);
            }
        }
        float zaa = 0.f, zba = 0.f, zab = 0.f, zbb = 0.f;
        #pragma unroll
        for (int k4 = 0; k4 < 7; ++k4) {
            const float4 pa = *(const float4*)&rows[l0][K1 + k4 * 4];
            const float4 pb = *(const float4*)&rows[l1][K1 + k4 * 4];
            const float* pav = (const float*)&pa;
            const float* pbv = (const float*)&pb;
            #pragma unroll
            for (int jj = 0; jj < 4; ++jj) {
                const int k = k4 * 4 + jj;
                if (k < K2) {
                    zaa = fmaf(pav[jj], w2[k],  zaa);
                    zba = fmaf(pav[jj], w2g[k], zba);
                    zab = fmaf(pbv[jj], w2[k],  zab);
                    zbb = fmaf(pbv[jj], w2g[k], zbb);
                }
            }
        }

        const float i0 = __builtin_amdgcn_rcpf(cd0);
        const float i1 = __builtin_amdgcn_rcpf(cd1);
        const float ga = g0a + g1a + (g2ta - g2sa) * i0;
        const float ma = m0a + m1a + (m2ta - m2sa) * i0;
        const float gb = g0b + g1b + (g2tb - g2sb) * i1;
        const float mb = m0b + m1b + (m2tb - m2sb) * i1;
        const float za = fsig(ga) * felu(ma) * (z1a + zaa * fsig(zba));
        const float zb = fsig(gb) * felu(mb) * (z1b + zab * fsig(zbb));

        // merge same-source runs across iterations (sorted -> long runs);
        // branches are on SGPR values -> wave-uniform, no divergence
        if (cs0 == run_s) {
            run_acc += za;
        } else {
            if (run_s >= 0) atomicAdd(x + (size_t)run_s * 128 + f, run_acc);
            run_s = cs0; run_acc = za;
        }
        if (cs1 == run_s) {
            run_acc += zb;
        } else {
            atomicAdd(x + (size_t)run_s * 128 + f, run_acc);
            run_s = cs1; run_acc = zb;
        }
    }
    atomicAdd(x + (size_t)run_s * 128 + f, run_acc);
}

// ---------------------------------------------------------------------------
// Pool + psi elementwise: T[n][3][128] = [x@Wp1, x@Wp2, x@Wpsi]
// pools[g] += elu(T0)*T1 ; xout = elu(T2)
// ---------------------------------------------------------------------------
__global__ __launch_bounds__(256) void pool_psi_kernel(
    const float* __restrict__ T, const int* __restrict__ gidx,
    float* __restrict__ pools, float* __restrict__ xout)
{
    int idx = blockIdx.x * 256 + threadIdx.x;
    int n = idx >> 7, f = idx & 127;
    float h1 = eluf(T[(size_t)n * 384 + f]);
    float h2 = T[(size_t)n * 384 + 128 + f];
    atomicAdd(pools + (size_t)gidx[n] * 128 + f, h1 * h2);
    xout[(size_t)n * 128 + f] = eluf(T[(size_t)n * 384 + 256 + f]);
}

// ---------------------------------------------------------------------------
// Final head: per graph: elu(@Wlr1[128,64]) -> elu(@Wlr2[64,42]) -> @Wlr3[42,1]
// ---------------------------------------------------------------------------
__global__ __launch_bounds__(64) void final_kernel(
    const float* __restrict__ pools,
    const float* __restrict__ Wlr1, const float* __restrict__ Wlr2,
    const float* __restrict__ Wlr3, float* __restrict__ out)
{
    __shared__ float h1[64];
    __shared__ float h2[42];
    const int g = blockIdx.x;
    const int f = threadIdx.x;

    float a = 0.f;
    #pragma unroll 8
    for (int k = 0; k < 128; ++k) a = fmaf(pools[(size_t)g * 128 + k], Wlr1[k * 64 + f], a);
    h1[f] = eluf(a);
    __syncthreads();
    if (f < 42) {
        float b = 0.f;
        #pragma unroll
        for (int k = 0; k < 64; ++k) b = fmaf(h1[k], Wlr2[k * 42 + f], b);
        h2[f] = eluf(b);
    }
    __syncthreads();
    if (f == 0) {
        float c = 0.f;
        #pragma unroll
        for (int k = 0; k < 42; ++k) c = fmaf(h2[k], Wlr3[k], c);
        out[g] = c;
    }
}

__global__ void zero_kernel(float* p, int n)
{
    int i = blockIdx.x * 256 + threadIdx.x;
    if (i < n) p[i] = 0.f;
}

extern "C" void kernel_launch(void* const* d_in, const int* in_sizes, int n_in,
                              void* d_out, int out_size, void* d_ws, size_t ws_size,
                              hipStream_t stream)
{
    const float* nodes = (const float*)d_in[0];
    const int*   esrc  = (const int*)d_in[1];
    const int*   etgt  = (const int*)d_in[2];
    const float* dist  = (const float*)d_in[3];
    const int*   gidx  = (const int*)d_in[4];
    // d_in[5] = node_counts : unused (division discarded in the source)
    const float* cs    = (const float*)d_in[6];
    const float* pw    = (const float*)d_in[7];
    const float* W_emb = (const float*)d_in[8];
    const float* Wg    = (const float*)d_in[9];
    const float* Wm    = (const float*)d_in[10];
    const float* W1v   = (const float*)d_in[11];
    const float* W2v   = (const float*)d_in[12];
    const float* W2vg  = (const float*)d_in[13];
    const float* Wp1   = (const float*)d_in[14];
    const float* Wp2   = (const float*)d_in[15];
    const float* Wpsi  = (const float*)d_in[16];
    const float* Wlr1  = (const float*)d_in[17];
    const float* Wlr2  = (const float*)d_in[18];
    const float* Wlr3  = (const float*)d_in[19];
    float* outp = (float*)d_out;

    // workspace layout (floats):
    // xA | xB | P(=T overlay) | pools | cnt | cursor | eperm | esrc_s | etgt_s | dist_s
    float* xA    = (float*)d_ws;
    float* xB    = xA + (size_t)NNODES * 128;
    float* P     = xB + (size_t)NNODES * 128;
    float* pools = P + (size_t)NNODES * 768;     // ~82 MB so far
    int* cnt     = (int*)(pools + NGRAPHS * 128);
    int* cursor  = cnt + NBINS;
    int* eperm   = cursor + NBINS;
    int* esrc_s  = eperm + NEDGES;
    int* etgt_s  = esrc_s + NEDGES;
    float* dist_s = (float*)(etgt_s + NEDGES);   // +5.3 MB total

    zero_kernel<<<100, 256, 0, stream>>>(pools, NGRAPHS * 128);

    // build source-sorted edge permutation (sources invariant across blocks)
    zero_kernel<<<(NBINS + 255) / 256, 256, 0, stream>>>((float*)cnt, NBINS);
    hist_kernel<<<(NEDGES + 255) / 256, 256, 0, stream>>>(esrc, cnt);
    scan_kernel<<<1, 1024, 0, stream>>>(cnt, cursor);
    scatter_kernel<<<(NEDGES + 255) / 256, 256, 0, stream>>>(esrc, cursor, eperm);
    reorder_meta_kernel<<<(NEDGES + 255) / 256, 256, 0, stream>>>(
        eperm, esrc, etgt, dist, esrc_s, etgt_s, dist_s);

    // x = sigmoid(nodes @ W_emb)
    {
        WPtrs wp{}; wp.w[0] = W_emb;
        gemm128_kernel<<<dim3(313, 2), 256, 0, stream>>>(nodes, wp, xA, 128, 1);
    }

    float* xc = xA;
    float* xn = xB;
    for (int i = 0; i < 3; ++i) {
        // P = x @ [Wg0,Wg1,Wg2,Wm0,Wm1,Wm2]  (each 128x128, contiguous in Wg/Wm)
        WPtrs wp{};
        const float* Wgi = Wg + (size_t)i * 49152;
        const float* Wmi = Wm + (size_t)i * 49152;
        wp.w[0] = Wgi;          wp.w[1] = Wgi + 16384;  wp.w[2] = Wgi + 32768;
        wp.w[3] = Wmi;          wp.w[4] = Wmi + 16384;  wp.w[5] = Wmi + 32768;
        gemm128_kernel<<<dim3(313, 12), 256, 0, stream>>>(xc, wp, P, 768, 0);

        // gather/combine/scatter over edges in source-sorted order
        edge_kernel<<<5000, 256, 0, stream>>>(P, eperm, esrc_s, etgt_s, dist_s,
            cs, pw,
            W1v + (size_t)i * (K1 * 128),
            W2v + (size_t)i * (K2 * 128),
            W2vg + (size_t)i * (K2 * 128), xc);

        // T = x @ [Wp1, Wp2, Wpsi]  (reuse P buffer)
        WPtrs wq{};
        wq.w[0] = Wp1 + (size_t)i * 16384;
        wq.w[1] = Wp2 + (size_t)i * 16384;
        wq.w[2] = Wpsi + (size_t)i * 16384;
        gemm128_kernel<<<dim3(313, 6), 256, 0, stream>>>(xc, wq, P, 384, 0);

        // pools[g] += elu(T0)*T1 ; xn = elu(T2)
        pool_psi_kernel<<<10000, 256, 0, stream>>>(P, gidx, pools, xn);

        float* tmp = xc; xc = xn; xn = tmp;
    }

    final_kernel<<<NGRAPHS, 64, 0, stream>>>(pools, Wlr1, Wlr2, Wlr3, outp);
}